// Round 1
// baseline (981.993 us; speedup 1.0000x reference)
//
#include <hip/hip_runtime.h>
#include <hip/hip_bf16.h>
#include <math.h>

#define B_ 4
#define S_ 1024
#define D_ 512
#define NH_ 8
#define DH_ 64
#define L_ 2
#define PRED_ 96
#define COUT_ 512

// ---------------- gates: ig/fg = gate_in . W + b, gate_in = [q, x, x] ----------------
__global__ __launch_bounds__(256) void gates_kernel(
    const float* __restrict__ q, const float* __restrict__ x,
    const float* __restrict__ Wig, const float* __restrict__ big,
    const float* __restrict__ Wfg, const float* __restrict__ bfg,
    float* __restrict__ ig_out, float* __restrict__ fg_out) {
  int bs = blockIdx.x;               // b*S + s
  int b = bs >> 10, s = bs & 1023;
  __shared__ float qs[D_], xs[D_];
  {
    const float* qrow = q + (size_t)bs * D_;
    const float* xrow = x + (size_t)bs * D_;
    for (int i = threadIdx.x; i < D_; i += 256) { qs[i] = qrow[i]; xs[i] = xrow[i]; }
  }
  __syncthreads();
  int wave = threadIdx.x >> 6, lane = threadIdx.x & 63;
  // 16 gate outputs (NH * {ig,fg}); 4 waves x 4 gates
  for (int gi = 0; gi < 4; ++gi) {
    int g = wave * 4 + gi;
    int h = g >> 1;
    bool isF = g & 1;
    const float* W = (isF ? Wfg : Wig) + (size_t)h * (3 * D_);
    float acc = 0.f;
    for (int e = lane; e < D_; e += 64)
      acc += W[e] * qs[e] + (W[D_ + e] + W[2 * D_ + e]) * xs[e];
#pragma unroll
    for (int off = 32; off; off >>= 1) acc += __shfl_down(acc, off);
    if (lane == 0) {
      float v = acc + (isF ? bfg : big)[h];
      (isF ? fg_out : ig_out)[((size_t)(b * NH_ + h)) * S_ + s] = v;
    }
  }
}

// ---------------- scan: F=cumsum(logsig(fg)); a=ig-F; amax=cummax(a); nmin=exp(-(F+amax)) ----------------
__global__ __launch_bounds__(64) void scan_kernel(
    const float* __restrict__ ig, const float* __restrict__ fg,
    float* __restrict__ a_out, float* __restrict__ amax_out,
    float* __restrict__ nmin_out) {
  int bh = blockIdx.x;               // b*NH + h
  int lane = threadIdx.x;            // 64
  const float* igr = ig + (size_t)bh * S_;
  const float* fgr = fg + (size_t)bh * S_;
  const int CH = S_ / 64;            // 16 per lane
  float lf[16], av[16], Fv[16];
  float lsum = 0.f;
  int base = lane * CH;
  for (int u = 0; u < CH; ++u) {
    float xv = fgr[base + u];
    // stable log_sigmoid
    float ls = (xv >= 0.f) ? -log1pf(__expf(-xv)) : (xv - log1pf(__expf(xv)));
    lf[u] = ls; lsum += ls;
  }
  // inclusive scan of lane sums -> exclusive prefix
  float pref = lsum;
#pragma unroll
  for (int off = 1; off < 64; off <<= 1) {
    float t = __shfl_up(pref, off);
    if (lane >= off) pref += t;
  }
  float F = pref - lsum;
  float lamax = -INFINITY;
  for (int u = 0; u < CH; ++u) {
    F += lf[u];
    Fv[u] = F;
    float a = igr[base + u] - F;
    av[u] = a;
    lamax = fmaxf(lamax, a);
  }
  float pmax = lamax;
#pragma unroll
  for (int off = 1; off < 64; off <<= 1) {
    float t = __shfl_up(pmax, off);
    if (lane >= off) pmax = fmaxf(pmax, t);
  }
  float run = __shfl_up(pmax, 1);
  if (lane == 0) run = -INFINITY;
  for (int u = 0; u < CH; ++u) {
    run = fmaxf(run, av[u]);
    size_t o = (size_t)bh * S_ + base + u;
    a_out[o] = av[u];
    amax_out[o] = run;
    nmin_out[o] = __expf(-(Fv[u] + run));
  }
}

// ---------------- causal weighted attention + normalizer + groupnorm ----------------
// per block: one (b, h, 32-row tile). k == v == x_enc so one LDS tile serves both.
__global__ __launch_bounds__(256) void attn_kernel(
    const float* __restrict__ q, const float* __restrict__ kv,
    const float* __restrict__ a_arr, const float* __restrict__ amax_arr,
    const float* __restrict__ nmin_arr, const float* __restrict__ lnw,
    float* __restrict__ out) {
  int it = blockIdx.x, h = blockIdx.y, b = blockIdx.z;
  int i0 = it * 32;
  __shared__ float Ks[32][65];   // pad 65: conflict-free column reads
  __shared__ float Ws[32][33];
  __shared__ float aj[32];
  int tid = threadIdx.x;
  int i = tid >> 3, dg = tid & 7;      // row i (0..31), d-group (8 floats each)
  size_t bh = (size_t)(b * NH_ + h) * S_;
  // q row in registers (64 f32)
  float qreg[64];
  {
    const float* qrow = q + ((size_t)(b * S_ + i0 + i)) * D_ + h * DH_;
#pragma unroll
    for (int d = 0; d < 64; ++d) qreg[d] = qrow[d];
  }
  float am_i = amax_arr[bh + i0 + i];
  float num[8];
#pragma unroll
  for (int u = 0; u < 8; ++u) num[u] = 0.f;
  float csum = 0.f;

  for (int jt = 0; jt <= it; ++jt) {
    int j0 = jt * 32;
    __syncthreads();  // protect Ks/Ws reuse from previous iteration
    for (int e = tid; e < 32 * 64; e += 256) {
      int r = e >> 6, d = e & 63;
      Ks[r][d] = kv[((size_t)(b * S_ + j0 + r)) * D_ + h * DH_ + d];
    }
    if (tid < 32) aj[tid] = a_arr[bh + j0 + tid];
    __syncthreads();
    // scores: each thread computes 4 entries of the 32x32 tile (row i, cols dg*4..+3)
    {
      int jb = dg * 4;
#pragma unroll
      for (int c = 0; c < 4; ++c) {
        int jj = jb + c;
        float s = 0.f;
#pragma unroll
        for (int d = 0; d < 64; ++d) s += qreg[d] * Ks[jj][d];
        float w = 0.f;
        if (j0 + jj <= i0 + i) w = s * 0.125f * __expf(aj[jj] - am_i);
        Ws[i][jj] = w;
      }
    }
    __syncthreads();
    // pv accumulate: thread owns (row i, cols dg*8..dg*8+7)
#pragma unroll 8
    for (int jj = 0; jj < 32; ++jj) {
      float w = Ws[i][jj];
      csum += w;  // every dg-thread of row i accumulates the same full row sum
#pragma unroll
      for (int u = 0; u < 8; ++u) num[u] += w * Ks[jj][dg * 8 + u];
    }
  }

  // epilogue: normalizer divide + MultiHeadLayerNorm over DH=64
  float norm = fmaxf(fabsf(csum), nmin_arr[bh + i0 + i]) + 1e-6f;
  float inv = 1.f / norm;
  float hv[8], s1 = 0.f, s2 = 0.f;
#pragma unroll
  for (int u = 0; u < 8; ++u) { hv[u] = num[u] * inv; s1 += hv[u]; s2 += hv[u] * hv[u]; }
#pragma unroll
  for (int off = 1; off < 8; off <<= 1) { s1 += __shfl_xor(s1, off); s2 += __shfl_xor(s2, off); }
  float mean = s1 * (1.f / 64.f);
  float var = s2 * (1.f / 64.f) - mean * mean;
  float rstd = rsqrtf(var + 1e-5f);
  float* orow = out + ((size_t)(b * S_ + i0 + i)) * D_ + h * DH_;
#pragma unroll
  for (int u = 0; u < 8; ++u)
    orow[dg * 8 + u] = (hv[u] - mean) * rstd * lnw[h * DH_ + dg * 8 + u];
}

// ---------------- final head: dec_out = q2[:, -96:, :] @ fc_W^T + fc_b ----------------
__global__ __launch_bounds__(256) void fc_kernel(
    const float* __restrict__ q2, const float* __restrict__ W,
    const float* __restrict__ bias, float* __restrict__ out) {
  int bp = blockIdx.x;               // b*PRED + p
  int b = bp / PRED_, p = bp % PRED_;
  int s = S_ - PRED_ + p;
  __shared__ float qs[D_];
  for (int i = threadIdx.x; i < D_; i += 256)
    qs[i] = q2[((size_t)(b * S_ + s)) * D_ + i];
  __syncthreads();
  for (int o = threadIdx.x; o < COUT_; o += 256) {
    float acc = bias[o];
    const float* Wr = W + (size_t)o * D_;
#pragma unroll 4
    for (int d = 0; d < D_; ++d) acc += Wr[d] * qs[d];
    out[(size_t)bp * COUT_ + o] = acc;
  }
}

extern "C" void kernel_launch(void* const* d_in, const int* in_sizes, int n_in,
                              void* d_out, int out_size, void* d_ws, size_t ws_size,
                              hipStream_t stream) {
  const float* x_enc = (const float*)d_in[0];
  const float* W_ig = (const float*)d_in[4];
  const float* b_ig = (const float*)d_in[5];
  const float* W_fg = (const float*)d_in[6];
  const float* b_fg = (const float*)d_in[7];
  const float* ln_w = (const float*)d_in[8];
  const float* fc_W = (const float*)d_in[9];
  const float* fc_b = (const float*)d_in[10];

  float* ws = (float*)d_ws;
  const size_t NBSD = (size_t)B_ * S_ * D_;   // 2,097,152 floats
  const size_t NBHS = (size_t)B_ * NH_ * S_;  // 32,768 floats
  float* h1 = ws;
  float* h2 = h1 + NBSD;
  float* ig = h2 + NBSD;
  float* fg = ig + NBHS;
  float* aA = fg + NBHS;
  float* amaxA = aA + NBHS;
  float* nminA = amaxA + NBHS;

  for (int l = 0; l < L_; ++l) {
    const float* qin = (l == 0) ? x_enc : h1;
    float* qout = (l == 0) ? h1 : h2;
    gates_kernel<<<B_ * S_, 256, 0, stream>>>(
        qin, x_enc,
        W_ig + (size_t)l * NH_ * 3 * D_, b_ig + (size_t)l * NH_,
        W_fg + (size_t)l * NH_ * 3 * D_, b_fg + (size_t)l * NH_, ig, fg);
    scan_kernel<<<B_ * NH_, 64, 0, stream>>>(ig, fg, aA, amaxA, nminA);
    attn_kernel<<<dim3(S_ / 32, NH_, B_), 256, 0, stream>>>(
        qin, x_enc, aA, amaxA, nminA, ln_w + (size_t)l * D_, qout);
  }
  fc_kernel<<<B_ * PRED_, 256, 0, stream>>>(h2, fc_W, fc_b, (float*)d_out);
}

// Round 6
// 350.765 us; speedup vs baseline: 2.7996x; 2.7996x over previous
//
#include <hip/hip_runtime.h>
#include <hip/hip_bf16.h>
#include <math.h>
#include <stdint.h>

#define B_ 4
#define S_ 1024
#define D_ 512
#define NH_ 8
#define DH_ 64
#define L_ 2
#define PRED_ 96
#define COUT_ 512

typedef __attribute__((ext_vector_type(8))) short short8;
typedef __attribute__((ext_vector_type(4))) float f32x4;

__device__ __forceinline__ unsigned short f2bf(float f) {
  union { float f; unsigned int u; } v; v.f = f;
  unsigned int r = v.u + 0x7fffu + ((v.u >> 16) & 1u);
  return (unsigned short)(r >> 16);
}
__device__ __forceinline__ float bf2f(unsigned short h) {
  union { unsigned int u; float f; } v; v.u = (unsigned int)h << 16;
  return v.f;
}

// ---------------- x_enc f32 [B,S,512] -> hi/lo bf16 [B*NH, S, 64] ----------------
__global__ __launch_bounds__(64) void convkv_kernel(
    const float* __restrict__ x, unsigned short* __restrict__ hiA,
    unsigned short* __restrict__ loA) {
  int bs = blockIdx.x;
  int b = bs >> 10, s = bs & 1023;
  int t = threadIdx.x;
  int h = t >> 3, dh0 = (t & 7) * 8;
  const float* src = x + (size_t)bs * D_ + t * 8;
  float4 v0 = *(const float4*)(src);
  float4 v1 = *(const float4*)(src + 4);
  float xv[8] = {v0.x, v0.y, v0.z, v0.w, v1.x, v1.y, v1.z, v1.w};
  unsigned short hh[8], ll[8];
#pragma unroll
  for (int k = 0; k < 8; ++k) {
    hh[k] = f2bf(xv[k]);
    ll[k] = f2bf(xv[k] - bf2f(hh[k]));
  }
  size_t off = (((size_t)(b * NH_ + h)) * S_ + s) * 64 + dh0;
  *(uint4*)(hiA + off) = *(const uint4*)hh;
  *(uint4*)(loA + off) = *(const uint4*)ll;
}

// ---------------- [B*NH,S,64] -> [B*NH,64,S] ----------------
__global__ __launch_bounds__(256) void transpose_kernel(
    const unsigned short* __restrict__ src_a, unsigned short* __restrict__ dst_a) {
  int jt = blockIdx.x, h = blockIdx.y, b = blockIdx.z;
  int bh = b * NH_ + h, j0 = jt * 64;
  __shared__ unsigned short tile[64][72];
  int t = threadIdx.x;
  {
    int j = t >> 2, dseg = (t & 3) * 16;
    const unsigned short* src = src_a + ((size_t)bh * S_ + j0 + j) * 64 + dseg;
    uint4 a0 = *(const uint4*)(src);
    uint4 a1 = *(const uint4*)(src + 8);
    *(uint4*)(&tile[j][dseg]) = a0;
    *(uint4*)(&tile[j][dseg + 8]) = a1;
  }
  __syncthreads();
  {
    int d = t >> 2, jseg = (t & 3) * 16;
    unsigned short us[16];
#pragma unroll
    for (int k = 0; k < 16; ++k) us[k] = tile[jseg + k][d];
    unsigned short* dst = dst_a + ((size_t)bh * 64 + d) * S_ + j0 + jseg;
    *(uint4*)(dst) = *(const uint4*)us;
    *(uint4*)(dst + 8) = *(const uint4*)(us + 8);
  }
}

// ---------------- gates ----------------
__global__ __launch_bounds__(256) void gates2_kernel(
    const float* __restrict__ q, const float* __restrict__ x,
    const float* __restrict__ Wig, const float* __restrict__ big,
    const float* __restrict__ Wfg, const float* __restrict__ bfg,
    float* __restrict__ ig_out, float* __restrict__ fg_out) {
  int sc = blockIdx.x, hg = blockIdx.y, b = blockIdx.z;
  __shared__ float Wq_s[8][512];
  __shared__ float Wc_s[8][512];
  for (int idx = threadIdx.x; idx < 8 * 512; idx += 256) {
    int p = idx >> 9, e = idx & 511;
    int h = hg * 4 + (p >> 1);
    const float* Wr = ((p & 1) ? Wfg : Wig) + (size_t)h * (3 * D_);
    Wq_s[p][e] = Wr[e];
    Wc_s[p][e] = Wr[512 + e] + Wr[1024 + e];
  }
  __syncthreads();
  int wv = threadIdx.x >> 6, l = threadIdx.x & 63;
  for (int rr = 0; rr < 8; ++rr) {
    int s = sc * 32 + wv * 8 + rr;
    const float* qrow = q + ((size_t)(b * S_ + s)) * D_;
    const float* xrow = x + ((size_t)(b * S_ + s)) * D_;
    float ql[8], xl[8];
#pragma unroll
    for (int k = 0; k < 8; ++k) { ql[k] = qrow[l + 64 * k]; xl[k] = xrow[l + 64 * k]; }
#pragma unroll
    for (int p = 0; p < 8; ++p) {
      float acc = 0.f;
#pragma unroll
      for (int k = 0; k < 8; ++k)
        acc += Wq_s[p][l + 64 * k] * ql[k] + Wc_s[p][l + 64 * k] * xl[k];
#pragma unroll
      for (int off = 32; off; off >>= 1) acc += __shfl_down(acc, off);
      if (l == 0) {
        int h = hg * 4 + (p >> 1);
        float v = acc + ((p & 1) ? bfg : big)[h];
        ((p & 1) ? fg_out : ig_out)[((size_t)(b * NH_ + h)) * S_ + s] = v;
      }
    }
  }
}

// ---------------- scan: a = ig - cumsum(logsig(fg)); amax = cummax(a) ----------------
__global__ __launch_bounds__(64) void scan_kernel(
    const float* __restrict__ ig, const float* __restrict__ fg,
    float* __restrict__ a_out, float* __restrict__ amax_out) {
  int bh = blockIdx.x;
  int lane = threadIdx.x;
  const float* igr = ig + (size_t)bh * S_;
  const float* fgr = fg + (size_t)bh * S_;
  const int CH = S_ / 64;
  float lf[16], av[16];
  float lsum = 0.f;
  int base = lane * CH;
  for (int u = 0; u < CH; ++u) {
    float xv = fgr[base + u];
    float ls = (xv >= 0.f) ? -log1pf(__expf(-xv)) : (xv - log1pf(__expf(xv)));
    lf[u] = ls; lsum += ls;
  }
  float pref = lsum;
#pragma unroll
  for (int off = 1; off < 64; off <<= 1) {
    float t = __shfl_up(pref, off);
    if (lane >= off) pref += t;
  }
  float F = pref - lsum;
  float lamax = -INFINITY;
  for (int u = 0; u < CH; ++u) {
    F += lf[u];
    float a = igr[base + u] - F;
    av[u] = a;
    lamax = fmaxf(lamax, a);
  }
  float pmax = lamax;
#pragma unroll
  for (int off = 1; off < 64; off <<= 1) {
    float t = __shfl_up(pmax, off);
    if (lane >= off) pmax = fmaxf(pmax, t);
  }
  float run = __shfl_up(pmax, 1);
  if (lane == 0) run = -INFINITY;
  for (int u = 0; u < CH; ++u) {
    run = fmaxf(run, av[u]);
    size_t o = (size_t)bh * S_ + base + u;
    a_out[o] = av[u];
    amax_out[o] = run;
  }
}

// ---------------- MFMA attention with hi/lo split; LN fused (normalizer cancels) ----------------
__global__ __launch_bounds__(256) void attn_mfma_kernel(
    const float* __restrict__ qin,
    const unsigned short* __restrict__ kH, const unsigned short* __restrict__ kL,
    const unsigned short* __restrict__ tH, const unsigned short* __restrict__ tL,
    const float* __restrict__ a_arr, const float* __restrict__ amax_arr,
    const float* __restrict__ lnw, float* __restrict__ out,
    int it0, int orow0, int out_srows) {
  int it = blockIdx.x + it0, h = blockIdx.y, b = blockIdx.z;
  int i0 = it * 64;
  int bh = b * NH_ + h;
  int tid = threadIdx.x;
  int w = tid >> 6, l = tid & 63;
  int l15 = l & 15, lg = l >> 4;

  __shared__ __align__(16) unsigned char smem[49152 + 256];
  unsigned char* KsH = smem;
  unsigned char* KsL = smem + 8192;
  unsigned char* VtH = smem + 16384;
  unsigned char* VtL = smem + 24576;
  unsigned char* PwH = smem + 32768 + w * 2048;
  unsigned char* PwL = smem + 40960 + w * 2048;
  float* aLds = (float*)(smem + 49152);

  // Q hi/lo fragments for row i0 + w*16 + l15
  short8 qh[2], qlo[2];
  {
    const float* qrow = qin + ((size_t)(b * S_ + i0 + w * 16 + l15)) * D_ + h * DH_;
#pragma unroll
    for (int ks = 0; ks < 2; ++ks) {
      const float* p = qrow + ks * 32 + lg * 8;
      float4 v0 = *(const float4*)(p);
      float4 v1 = *(const float4*)(p + 4);
      float xv[8] = {v0.x, v0.y, v0.z, v0.w, v1.x, v1.y, v1.z, v1.w};
      unsigned short hh[8], ll[8];
#pragma unroll
      for (int k = 0; k < 8; ++k) {
        hh[k] = f2bf(xv[k]);
        ll[k] = f2bf(xv[k] - bf2f(hh[k]));
      }
      qh[ks] = *(const short8*)hh;
      qlo[ks] = *(const short8*)ll;
    }
  }
  float am_i = amax_arr[(size_t)bh * S_ + i0 + w * 16 + l15];
  const float* abase = a_arr + (size_t)bh * S_;

  f32x4 acc[4];
#pragma unroll
  for (int nt = 0; nt < 4; ++nt) acc[nt] = (f32x4){0.f, 0.f, 0.f, 0.f};

  const unsigned short* KsrcH = kH + (size_t)bh * S_ * 64;
  const unsigned short* KsrcL = kL + (size_t)bh * S_ * 64;
  const unsigned short* TsrcH = tH + (size_t)bh * 64 * S_;
  const unsigned short* TsrcL = tL + (size_t)bh * 64 * S_;

  for (int jt = 0; jt <= it; ++jt) {
    int j0 = jt * 64;
    __syncthreads();
    {
      int r = w * 16 + l15;
#pragma unroll
      for (int gb = 0; gb < 8; gb += 4) {
        int g = gb + lg;
        int sw = r * 128 + ((g ^ (r & 7)) * 16);
        *(uint4*)(KsH + sw) = *(const uint4*)(KsrcH + ((size_t)(j0 + r)) * 64 + g * 8);
        *(uint4*)(KsL + sw) = *(const uint4*)(KsrcL + ((size_t)(j0 + r)) * 64 + g * 8);
        *(uint4*)(VtH + sw) = *(const uint4*)(TsrcH + (size_t)r * S_ + j0 + g * 8);
        *(uint4*)(VtL + sw) = *(const uint4*)(TsrcL + (size_t)r * S_ + j0 + g * 8);
      }
    }
    if (tid < 64) aLds[tid] = abase[j0 + tid];
    __syncthreads();
    int i_g = i0 + w * 16 + l15;
    // scores S^T = K . Q^T with hi/lo cross terms
#pragma unroll
    for (int js = 0; js < 4; ++js) {
      f32x4 st = (f32x4){0.f, 0.f, 0.f, 0.f};
      int krow = js * 16 + l15;
      int key = krow & 7;
      short8 kh0 = *(const short8*)(KsH + krow * 128 + (((0 + lg) ^ key) * 16));
      short8 kh1 = *(const short8*)(KsH + krow * 128 + (((4 + lg) ^ key) * 16));
      short8 kl0 = *(const short8*)(KsL + krow * 128 + (((0 + lg) ^ key) * 16));
      short8 kl1 = *(const short8*)(KsL + krow * 128 + (((4 + lg) ^ key) * 16));
      st = __builtin_amdgcn_mfma_f32_16x16x32_bf16(kh0, qh[0], st, 0, 0, 0);
      st = __builtin_amdgcn_mfma_f32_16x16x32_bf16(kh1, qh[1], st, 0, 0, 0);
      st = __builtin_amdgcn_mfma_f32_16x16x32_bf16(kh0, qlo[0], st, 0, 0, 0);
      st = __builtin_amdgcn_mfma_f32_16x16x32_bf16(kh1, qlo[1], st, 0, 0, 0);
      st = __builtin_amdgcn_mfma_f32_16x16x32_bf16(kl0, qh[0], st, 0, 0, 0);
      st = __builtin_amdgcn_mfma_f32_16x16x32_bf16(kl1, qh[1], st, 0, 0, 0);
      int jb_loc = js * 16 + lg * 4;
      unsigned int pkh[2], pkl[2];
#pragma unroll
      for (int r2 = 0; r2 < 2; ++r2) {
        unsigned int ph = 0, pl = 0;
#pragma unroll
        for (int rr = 0; rr < 2; ++rr) {
          int r = r2 * 2 + rr;
          int jl = jb_loc + r;
          float e = __expf(fminf(aLds[jl] - am_i, 0.f));
          float wv = (j0 + jl <= i_g) ? st[r] * 0.125f * e : 0.f;
          unsigned short whi = f2bf(wv);
          unsigned short wlo = f2bf(wv - bf2f(whi));
          ph |= (unsigned int)whi << (rr * 16);
          pl |= (unsigned int)wlo << (rr * 16);
        }
        pkh[r2] = ph; pkl[r2] = pl;
      }
      int g = js * 2 + (lg >> 1);
      int pw_off = l15 * 128 + ((g ^ (l15 & 7)) * 16) + (lg & 1) * 8;
      *(uint2*)(PwH + pw_off) = make_uint2(pkh[0], pkh[1]);
      *(uint2*)(PwL + pw_off) = make_uint2(pkl[0], pkl[1]);
    }
    // PV with hi/lo cross terms
#pragma unroll
    for (int ks = 0; ks < 2; ++ks) {
      int pg = ((ks * 4 + lg) ^ (l15 & 7)) * 16;
      short8 ph = *(const short8*)(PwH + l15 * 128 + pg);
      short8 pl = *(const short8*)(PwL + l15 * 128 + pg);
#pragma unroll
      for (int nt = 0; nt < 4; ++nt) {
        int vr = nt * 16 + l15;
        int vg = vr * 128 + (((ks * 4 + lg) ^ (vr & 7)) * 16);
        short8 vh = *(const short8*)(VtH + vg);
        short8 vl = *(const short8*)(VtL + vg);
        acc[nt] = __builtin_amdgcn_mfma_f32_16x16x32_bf16(ph, vh, acc[nt], 0, 0, 0);
        acc[nt] = __builtin_amdgcn_mfma_f32_16x16x32_bf16(pl, vh, acc[nt], 0, 0, 0);
        acc[nt] = __builtin_amdgcn_mfma_f32_16x16x32_bf16(ph, vl, acc[nt], 0, 0, 0);
      }
    }
  }

  // epilogue: LN only (normalizer is scale-invariant under LN)
  float lw[4];
#pragma unroll
  for (int nt = 0; nt < 4; ++nt) lw[nt] = lnw[h * DH_ + nt * 16 + l15];
#pragma unroll
  for (int r = 0; r < 4; ++r) {
    int il = lg * 4 + r;
    int i_glob = i0 + w * 16 + il;
    float hv[4], s1 = 0.f, s2 = 0.f;
#pragma unroll
    for (int nt = 0; nt < 4; ++nt) {
      hv[nt] = acc[nt][r];
      s1 += hv[nt]; s2 += hv[nt] * hv[nt];
    }
#pragma unroll
    for (int off = 1; off < 16; off <<= 1) {
      s1 += __shfl_xor(s1, off); s2 += __shfl_xor(s2, off);
    }
    float mean = s1 * (1.f / 64.f);
    float var = s2 * (1.f / 64.f) - mean * mean;
    float rstd = rsqrtf(var + 1e-5f);
    float* orow = out + ((size_t)(b * out_srows + (i_glob - orow0))) * D_ + h * DH_;
#pragma unroll
    for (int nt = 0; nt < 4; ++nt)
      orow[nt * 16 + l15] = (hv[nt] - mean) * rstd * lw[nt];
  }
}

// ---------------- final head: q2c is [B,128,512] (rows 896..1023) ----------------
__global__ __launch_bounds__(256) void fc2_kernel(
    const float* __restrict__ q2c, const float* __restrict__ W,
    const float* __restrict__ bias, float* __restrict__ out) {
  int blk = blockIdx.x;
  __shared__ float qs[3][512];
  for (int idx = threadIdx.x; idx < 3 * 512; idx += 256) {
    int rr = idx >> 9, e = idx & 511;
    int bp = blk * 3 + rr;
    int b = bp / PRED_, pcol = bp % PRED_;
    qs[rr][e] = q2c[((size_t)(b * 128 + 32 + pcol)) * D_ + e];
  }
  __syncthreads();
  int wv = threadIdx.x >> 6, l = threadIdx.x & 63;
  for (int o = wv; o < COUT_; o += 4) {
    const float* Wr = W + (size_t)o * D_;
    float a0 = 0.f, a1 = 0.f, a2 = 0.f;
#pragma unroll
    for (int k = 0; k < 8; ++k) {
      float wvv = Wr[l + 64 * k];
      a0 += wvv * qs[0][l + 64 * k];
      a1 += wvv * qs[1][l + 64 * k];
      a2 += wvv * qs[2][l + 64 * k];
    }
#pragma unroll
    for (int off = 32; off; off >>= 1) {
      a0 += __shfl_down(a0, off); a1 += __shfl_down(a1, off); a2 += __shfl_down(a2, off);
    }
    if (l == 0) {
      float bs = bias[o];
      float av[3] = {a0, a1, a2};
      for (int rr = 0; rr < 3; ++rr)
        out[(size_t)(blk * 3 + rr) * COUT_ + o] = av[rr] + bs;
    }
  }
}

extern "C" void kernel_launch(void* const* d_in, const int* in_sizes, int n_in,
                              void* d_out, int out_size, void* d_ws, size_t ws_size,
                              hipStream_t stream) {
  const float* x_enc = (const float*)d_in[0];
  const float* W_ig = (const float*)d_in[4];
  const float* b_ig = (const float*)d_in[5];
  const float* W_fg = (const float*)d_in[6];
  const float* b_fg = (const float*)d_in[7];
  const float* ln_w = (const float*)d_in[8];
  const float* fc_W = (const float*)d_in[9];
  const float* fc_b = (const float*)d_in[10];

  float* ws = (float*)d_ws;
  const size_t NBSD = (size_t)B_ * S_ * D_;   // 2,097,152
  const size_t NBHS = (size_t)B_ * NH_ * S_;  // 32,768
  float* h1 = ws;                      // [B,S,D] f32
  float* h2c = h1 + NBSD;              // [B,128,D] f32 (rows 896..1023)
  float* ig = h2c + (size_t)B_ * 128 * D_;
  float* fg = ig + NBHS;
  float* aA = fg + NBHS;
  float* amaxA = aA + NBHS;
  unsigned short* kvhH = (unsigned short*)(amaxA + NBHS);
  unsigned short* kvhL = kvhH + NBSD;
  unsigned short* kvTH = kvhL + NBSD;
  unsigned short* kvTL = kvTH + NBSD;

  convkv_kernel<<<B_ * S_, 64, 0, stream>>>(x_enc, kvhH, kvhL);
  transpose_kernel<<<dim3(S_ / 64, NH_, B_), 256, 0, stream>>>(kvhH, kvTH);
  transpose_kernel<<<dim3(S_ / 64, NH_, B_), 256, 0, stream>>>(kvhL, kvTL);

  for (int l = 0; l < L_; ++l) {
    const float* qin = (l == 0) ? x_enc : h1;
    gates2_kernel<<<dim3(S_ / 32, 2, B_), 256, 0, stream>>>(
        qin, x_enc,
        W_ig + (size_t)l * NH_ * 3 * D_, b_ig + (size_t)l * NH_,
        W_fg + (size_t)l * NH_ * 3 * D_, b_fg + (size_t)l * NH_, ig, fg);
    scan_kernel<<<B_ * NH_, 64, 0, stream>>>(ig, fg, aA, amaxA);
    if (l == 0) {
      attn_mfma_kernel<<<dim3(S_ / 64, NH_, B_), 256, 0, stream>>>(
          qin, kvhH, kvhL, kvTH, kvTL, aA, amaxA, ln_w + (size_t)l * D_,
          h1, 0, 0, S_);
    } else {
      attn_mfma_kernel<<<dim3(2, NH_, B_), 256, 0, stream>>>(
          qin, kvhH, kvhL, kvTH, kvTL, aA, amaxA, ln_w + (size_t)l * D_,
          h2c, 14, 896, 128);
    }
  }
  fc2_kernel<<<B_ * PRED_ / 3, 256, 0, stream>>>(h2c, fc_W, fc_b, (float*)d_out);
}

// Round 9
// 299.040 us; speedup vs baseline: 3.2838x; 1.1730x over previous
//
#include <hip/hip_runtime.h>
#include <hip/hip_bf16.h>
#include <math.h>
#include <stdint.h>

#define B_ 4
#define S_ 1024
#define D_ 512
#define NH_ 8
#define DH_ 64
#define L_ 2
#define PRED_ 96
#define COUT_ 512

typedef __attribute__((ext_vector_type(8))) short short8;
typedef __attribute__((ext_vector_type(4))) float f32x4;

__device__ __forceinline__ unsigned short f2bf(float f) {
  union { float f; unsigned int u; } v; v.f = f;
  unsigned int r = v.u + 0x7fffu + ((v.u >> 16) & 1u);
  return (unsigned short)(r >> 16);
}
__device__ __forceinline__ float bf2f(unsigned short h) {
  union { unsigned int u; float f; } v; v.u = (unsigned int)h << 16;
  return v.f;
}

// ---------------- x_enc f32 [B,S,512] -> hi/lo bf16 [B*NH, S, 64] ----------------
__global__ __launch_bounds__(64) void convkv_kernel(
    const float* __restrict__ x, unsigned short* __restrict__ hiA,
    unsigned short* __restrict__ loA) {
  int bs = blockIdx.x;
  int b = bs >> 10, s = bs & 1023;
  int t = threadIdx.x;
  int h = t >> 3, dh0 = (t & 7) * 8;
  const float* src = x + (size_t)bs * D_ + t * 8;
  float4 v0 = *(const float4*)(src);
  float4 v1 = *(const float4*)(src + 4);
  float xv[8] = {v0.x, v0.y, v0.z, v0.w, v1.x, v1.y, v1.z, v1.w};
  unsigned short hh[8], ll[8];
#pragma unroll
  for (int k = 0; k < 8; ++k) {
    hh[k] = f2bf(xv[k]);
    ll[k] = f2bf(xv[k] - bf2f(hh[k]));
  }
  size_t off = (((size_t)(b * NH_ + h)) * S_ + s) * 64 + dh0;
  *(uint4*)(hiA + off) = *(const uint4*)hh;
  *(uint4*)(loA + off) = *(const uint4*)ll;
}

// ---------------- [B*NH,S,64] -> [B*NH,64,S] ----------------
__global__ __launch_bounds__(256) void transpose_kernel(
    const unsigned short* __restrict__ src_a, unsigned short* __restrict__ dst_a) {
  int jt = blockIdx.x, h = blockIdx.y, b = blockIdx.z;
  int bh = b * NH_ + h, j0 = jt * 64;
  __shared__ unsigned short tile[64][72];
  int t = threadIdx.x;
  {
    int j = t >> 2, dseg = (t & 3) * 16;
    const unsigned short* src = src_a + ((size_t)bh * S_ + j0 + j) * 64 + dseg;
    uint4 a0 = *(const uint4*)(src);
    uint4 a1 = *(const uint4*)(src + 8);
    *(uint4*)(&tile[j][dseg]) = a0;
    *(uint4*)(&tile[j][dseg + 8]) = a1;
  }
  __syncthreads();
  {
    int d = t >> 2, jseg = (t & 3) * 16;
    unsigned short us[16];
#pragma unroll
    for (int k = 0; k < 16; ++k) us[k] = tile[jseg + k][d];
    unsigned short* dst = dst_a + ((size_t)bh * 64 + d) * S_ + j0 + jseg;
    *(uint4*)(dst) = *(const uint4*)us;
    *(uint4*)(dst + 8) = *(const uint4*)(us + 8);
  }
}

// ---------------- gates ----------------
__global__ __launch_bounds__(256) void gates2_kernel(
    const float* __restrict__ q, const float* __restrict__ x,
    const float* __restrict__ Wig, const float* __restrict__ big,
    const float* __restrict__ Wfg, const float* __restrict__ bfg,
    float* __restrict__ ig_out, float* __restrict__ fg_out) {
  int sc = blockIdx.x, hg = blockIdx.y, b = blockIdx.z;
  __shared__ float Wq_s[8][512];
  __shared__ float Wc_s[8][512];
  for (int idx = threadIdx.x; idx < 8 * 512; idx += 256) {
    int p = idx >> 9, e = idx & 511;
    int h = hg * 4 + (p >> 1);
    const float* Wr = ((p & 1) ? Wfg : Wig) + (size_t)h * (3 * D_);
    Wq_s[p][e] = Wr[e];
    Wc_s[p][e] = Wr[512 + e] + Wr[1024 + e];
  }
  __syncthreads();
  int wv = threadIdx.x >> 6, l = threadIdx.x & 63;
  for (int rr = 0; rr < 8; ++rr) {
    int s = sc * 32 + wv * 8 + rr;
    const float* qrow = q + ((size_t)(b * S_ + s)) * D_;
    const float* xrow = x + ((size_t)(b * S_ + s)) * D_;
    float ql[8], xl[8];
#pragma unroll
    for (int k = 0; k < 8; ++k) { ql[k] = qrow[l + 64 * k]; xl[k] = xrow[l + 64 * k]; }
#pragma unroll
    for (int p = 0; p < 8; ++p) {
      float acc = 0.f;
#pragma unroll
      for (int k = 0; k < 8; ++k)
        acc += Wq_s[p][l + 64 * k] * ql[k] + Wc_s[p][l + 64 * k] * xl[k];
#pragma unroll
      for (int off = 32; off; off >>= 1) acc += __shfl_down(acc, off);
      if (l == 0) {
        int h = hg * 4 + (p >> 1);
        float v = acc + ((p & 1) ? bfg : big)[h];
        ((p & 1) ? fg_out : ig_out)[((size_t)(b * NH_ + h)) * S_ + s] = v;
      }
    }
  }
}

// ---------------- scan: a = ig - cumsum(logsig(fg)); amax = cummax(a) ----------------
__global__ __launch_bounds__(64) void scan_kernel(
    const float* __restrict__ ig, const float* __restrict__ fg,
    float* __restrict__ a_out, float* __restrict__ amax_out) {
  int bh = blockIdx.x;
  int lane = threadIdx.x;
  const float* igr = ig + (size_t)bh * S_;
  const float* fgr = fg + (size_t)bh * S_;
  const int CH = S_ / 64;
  float lf[16], av[16];
  float lsum = 0.f;
  int base = lane * CH;
  for (int u = 0; u < CH; ++u) {
    float xv = fgr[base + u];
    float ls = (xv >= 0.f) ? -log1pf(__expf(-xv)) : (xv - log1pf(__expf(xv)));
    lf[u] = ls; lsum += ls;
  }
  float pref = lsum;
#pragma unroll
  for (int off = 1; off < 64; off <<= 1) {
    float t = __shfl_up(pref, off);
    if (lane >= off) pref += t;
  }
  float F = pref - lsum;
  float lamax = -INFINITY;
  for (int u = 0; u < CH; ++u) {
    F += lf[u];
    float a = igr[base + u] - F;
    av[u] = a;
    lamax = fmaxf(lamax, a);
  }
  float pmax = lamax;
#pragma unroll
  for (int off = 1; off < 64; off <<= 1) {
    float t = __shfl_up(pmax, off);
    if (lane >= off) pmax = fmaxf(pmax, t);
  }
  float run = __shfl_up(pmax, 1);
  if (lane == 0) run = -INFINITY;
  for (int u = 0; u < CH; ++u) {
    run = fmaxf(run, av[u]);
    size_t o = (size_t)bh * S_ + base + u;
    a_out[o] = av[u];
    amax_out[o] = run;
  }
}

// ---------------- MFMA attention with hi/lo split; LN fused (normalizer cancels) ----------------
// write_bf==0: f32 out; write_bf!=0: bf16 hi/lo out (for fc consumption)
__global__ __launch_bounds__(256) void attn_mfma_kernel(
    const float* __restrict__ qin,
    const unsigned short* __restrict__ kH, const unsigned short* __restrict__ kL,
    const unsigned short* __restrict__ tH, const unsigned short* __restrict__ tL,
    const float* __restrict__ a_arr, const float* __restrict__ amax_arr,
    const float* __restrict__ lnw, float* __restrict__ out,
    unsigned short* __restrict__ outH, unsigned short* __restrict__ outL,
    int write_bf, int it0, int orow0, int out_srows) {
  int it = blockIdx.x + it0, h = blockIdx.y, b = blockIdx.z;
  int i0 = it * 64;
  int bh = b * NH_ + h;
  int tid = threadIdx.x;
  int w = tid >> 6, l = tid & 63;
  int l15 = l & 15, lg = l >> 4;

  __shared__ __align__(16) unsigned char smem[49152 + 256];
  unsigned char* KsH = smem;
  unsigned char* KsL = smem + 8192;
  unsigned char* VtH = smem + 16384;
  unsigned char* VtL = smem + 24576;
  unsigned char* PwH = smem + 32768 + w * 2048;
  unsigned char* PwL = smem + 40960 + w * 2048;
  float* aLds = (float*)(smem + 49152);

  // Q hi/lo fragments for row i0 + w*16 + l15
  short8 qh[2], qlo[2];
  {
    const float* qrow = qin + ((size_t)(b * S_ + i0 + w * 16 + l15)) * D_ + h * DH_;
#pragma unroll
    for (int ks = 0; ks < 2; ++ks) {
      const float* p = qrow + ks * 32 + lg * 8;
      float4 v0 = *(const float4*)(p);
      float4 v1 = *(const float4*)(p + 4);
      float xv[8] = {v0.x, v0.y, v0.z, v0.w, v1.x, v1.y, v1.z, v1.w};
      unsigned short hh[8], ll[8];
#pragma unroll
      for (int k = 0; k < 8; ++k) {
        hh[k] = f2bf(xv[k]);
        ll[k] = f2bf(xv[k] - bf2f(hh[k]));
      }
      qh[ks] = *(const short8*)hh;
      qlo[ks] = *(const short8*)ll;
    }
  }
  float am_i = amax_arr[(size_t)bh * S_ + i0 + w * 16 + l15];
  const float* abase = a_arr + (size_t)bh * S_;

  f32x4 acc[4];
#pragma unroll
  for (int nt = 0; nt < 4; ++nt) acc[nt] = (f32x4){0.f, 0.f, 0.f, 0.f};

  const unsigned short* KsrcH = kH + (size_t)bh * S_ * 64;
  const unsigned short* KsrcL = kL + (size_t)bh * S_ * 64;
  const unsigned short* TsrcH = tH + (size_t)bh * 64 * S_;
  const unsigned short* TsrcL = tL + (size_t)bh * 64 * S_;

  for (int jt = 0; jt <= it; ++jt) {
    int j0 = jt * 64;
    __syncthreads();
    {
      int r = w * 16 + l15;
#pragma unroll
      for (int gb = 0; gb < 8; gb += 4) {
        int g = gb + lg;
        int sw = r * 128 + ((g ^ (r & 7)) * 16);
        *(uint4*)(KsH + sw) = *(const uint4*)(KsrcH + ((size_t)(j0 + r)) * 64 + g * 8);
        *(uint4*)(KsL + sw) = *(const uint4*)(KsrcL + ((size_t)(j0 + r)) * 64 + g * 8);
        *(uint4*)(VtH + sw) = *(const uint4*)(TsrcH + (size_t)r * S_ + j0 + g * 8);
        *(uint4*)(VtL + sw) = *(const uint4*)(TsrcL + (size_t)r * S_ + j0 + g * 8);
      }
    }
    if (tid < 64) aLds[tid] = abase[j0 + tid];
    __syncthreads();
    int i_g = i0 + w * 16 + l15;
    // scores S^T = K . Q^T with hi/lo cross terms
#pragma unroll
    for (int js = 0; js < 4; ++js) {
      f32x4 st = (f32x4){0.f, 0.f, 0.f, 0.f};
      int krow = js * 16 + l15;
      int key = krow & 7;
      short8 kh0 = *(const short8*)(KsH + krow * 128 + (((0 + lg) ^ key) * 16));
      short8 kh1 = *(const short8*)(KsH + krow * 128 + (((4 + lg) ^ key) * 16));
      short8 kl0 = *(const short8*)(KsL + krow * 128 + (((0 + lg) ^ key) * 16));
      short8 kl1 = *(const short8*)(KsL + krow * 128 + (((4 + lg) ^ key) * 16));
      st = __builtin_amdgcn_mfma_f32_16x16x32_bf16(kh0, qh[0], st, 0, 0, 0);
      st = __builtin_amdgcn_mfma_f32_16x16x32_bf16(kh1, qh[1], st, 0, 0, 0);
      st = __builtin_amdgcn_mfma_f32_16x16x32_bf16(kh0, qlo[0], st, 0, 0, 0);
      st = __builtin_amdgcn_mfma_f32_16x16x32_bf16(kh1, qlo[1], st, 0, 0, 0);
      st = __builtin_amdgcn_mfma_f32_16x16x32_bf16(kl0, qh[0], st, 0, 0, 0);
      st = __builtin_amdgcn_mfma_f32_16x16x32_bf16(kl1, qh[1], st, 0, 0, 0);
      int jb_loc = js * 16 + lg * 4;
      unsigned int pkh[2], pkl[2];
#pragma unroll
      for (int r2 = 0; r2 < 2; ++r2) {
        unsigned int ph = 0, pl = 0;
#pragma unroll
        for (int rr = 0; rr < 2; ++rr) {
          int r = r2 * 2 + rr;
          int jl = jb_loc + r;
          float e = __expf(fminf(aLds[jl] - am_i, 0.f));
          float wv = (j0 + jl <= i_g) ? st[r] * 0.125f * e : 0.f;
          unsigned short whi = f2bf(wv);
          unsigned short wlo = f2bf(wv - bf2f(whi));
          ph |= (unsigned int)whi << (rr * 16);
          pl |= (unsigned int)wlo << (rr * 16);
        }
        pkh[r2] = ph; pkl[r2] = pl;
      }
      int g = js * 2 + (lg >> 1);
      int pw_off = l15 * 128 + ((g ^ (l15 & 7)) * 16) + (lg & 1) * 8;
      *(uint2*)(PwH + pw_off) = make_uint2(pkh[0], pkh[1]);
      *(uint2*)(PwL + pw_off) = make_uint2(pkl[0], pkl[1]);
    }
    // PV with hi/lo cross terms
#pragma unroll
    for (int ks = 0; ks < 2; ++ks) {
      int pg = ((ks * 4 + lg) ^ (l15 & 7)) * 16;
      short8 ph = *(const short8*)(PwH + l15 * 128 + pg);
      short8 pl = *(const short8*)(PwL + l15 * 128 + pg);
#pragma unroll
      for (int nt = 0; nt < 4; ++nt) {
        int vr = nt * 16 + l15;
        int vg = vr * 128 + (((ks * 4 + lg) ^ (vr & 7)) * 16);
        short8 vh = *(const short8*)(VtH + vg);
        short8 vl = *(const short8*)(VtL + vg);
        acc[nt] = __builtin_amdgcn_mfma_f32_16x16x32_bf16(ph, vh, acc[nt], 0, 0, 0);
        acc[nt] = __builtin_amdgcn_mfma_f32_16x16x32_bf16(pl, vh, acc[nt], 0, 0, 0);
        acc[nt] = __builtin_amdgcn_mfma_f32_16x16x32_bf16(ph, vl, acc[nt], 0, 0, 0);
      }
    }
  }

  // epilogue: LN only (normalizer is scale-invariant under LN)
  float lw[4];
#pragma unroll
  for (int nt = 0; nt < 4; ++nt) lw[nt] = lnw[h * DH_ + nt * 16 + l15];
#pragma unroll
  for (int r = 0; r < 4; ++r) {
    int il = lg * 4 + r;
    int i_glob = i0 + w * 16 + il;
    float hv[4], s1 = 0.f, s2 = 0.f;
#pragma unroll
    for (int nt = 0; nt < 4; ++nt) {
      hv[nt] = acc[nt][r];
      s1 += hv[nt]; s2 += hv[nt] * hv[nt];
    }
#pragma unroll
    for (int off = 1; off < 16; off <<= 1) {
      s1 += __shfl_xor(s1, off); s2 += __shfl_xor(s2, off);
    }
    float mean = s1 * (1.f / 64.f);
    float var = s2 * (1.f / 64.f) - mean * mean;
    float rstd = rsqrtf(var + 1e-5f);
    size_t ro = ((size_t)(b * out_srows + (i_glob - orow0))) * D_ + h * DH_;
    if (!write_bf) {
#pragma unroll
      for (int nt = 0; nt < 4; ++nt)
        out[ro + nt * 16 + l15] = (hv[nt] - mean) * rstd * lw[nt];
    } else {
#pragma unroll
      for (int nt = 0; nt < 4; ++nt) {
        float v = (hv[nt] - mean) * rstd * lw[nt];
        unsigned short hi = f2bf(v);
        outH[ro + nt * 16 + l15] = hi;
        outL[ro + nt * 16 + l15] = f2bf(v - bf2f(hi));
      }
    }
  }
}

// ---------------- final head via MFMA: out[384,512] = q2 . W^T + b ----------------
// qH/qL: [B,128,512] bf16 (rows 896..1023 of layer-2 output); W: f32 [512,512],
// split to hi/lo bf16 inline in registers.
__global__ __launch_bounds__(256) void fc3_kernel(
    const unsigned short* __restrict__ qH, const unsigned short* __restrict__ qL,
    const float* __restrict__ W, const float* __restrict__ bias,
    float* __restrict__ out) {
  int rt = blockIdx.x, ot = blockIdx.y;
  int tid = threadIdx.x;
  int w = tid >> 6, l = tid & 63, l15 = l & 15, lg = l >> 4;
  int r_flat = rt * 64 + w * 16 + l15;     // A-operand row this lane loads
  int b = r_flat / 96, pc = r_flat - b * 96;
  const unsigned short* qHrow = qH + ((size_t)(b * 128 + 32 + pc)) * D_;
  const unsigned short* qLrow = qL + ((size_t)(b * 128 + 32 + pc)) * D_;
  int obase = ot * 64;

  f32x4 acc[4];
#pragma unroll
  for (int og = 0; og < 4; ++og) acc[og] = (f32x4){0.f, 0.f, 0.f, 0.f};

#pragma unroll 2
  for (int ks = 0; ks < 16; ++ks) {
    int k0 = ks * 32 + lg * 8;
    short8 ah = *(const short8*)(qHrow + k0);
    short8 al = *(const short8*)(qLrow + k0);
#pragma unroll
    for (int og = 0; og < 4; ++og) {
      const float* wrow = W + (size_t)(obase + og * 16 + l15) * D_ + k0;
      float4 w0 = *(const float4*)(wrow);
      float4 w1 = *(const float4*)(wrow + 4);
      float wv[8] = {w0.x, w0.y, w0.z, w0.w, w1.x, w1.y, w1.z, w1.w};
      unsigned short bhh[8], bll[8];
#pragma unroll
      for (int k = 0; k < 8; ++k) {
        bhh[k] = f2bf(wv[k]);
        bll[k] = f2bf(wv[k] - bf2f(bhh[k]));
      }
      short8 bh = *(const short8*)bhh;
      short8 bl = *(const short8*)bll;
      acc[og] = __builtin_amdgcn_mfma_f32_16x16x32_bf16(ah, bh, acc[og], 0, 0, 0);
      acc[og] = __builtin_amdgcn_mfma_f32_16x16x32_bf16(al, bh, acc[og], 0, 0, 0);
      acc[og] = __builtin_amdgcn_mfma_f32_16x16x32_bf16(ah, bl, acc[og], 0, 0, 0);
    }
  }
  // D[m][n]: m (row, lg*4+r) = A-operand (q) row; n (col, l15) = B-operand (W) row
  int rbase = rt * 64 + w * 16 + lg * 4;
#pragma unroll
  for (int og = 0; og < 4; ++og) {
    int o = obase + og * 16 + l15;
    float bs = bias[o];
#pragma unroll
    for (int r = 0; r < 4; ++r)
      out[(size_t)(rbase + r) * COUT_ + o] = acc[og][r] + bs;
  }
}

extern "C" void kernel_launch(void* const* d_in, const int* in_sizes, int n_in,
                              void* d_out, int out_size, void* d_ws, size_t ws_size,
                              hipStream_t stream) {
  const float* x_enc = (const float*)d_in[0];
  const float* W_ig = (const float*)d_in[4];
  const float* b_ig = (const float*)d_in[5];
  const float* W_fg = (const float*)d_in[6];
  const float* b_fg = (const float*)d_in[7];
  const float* ln_w = (const float*)d_in[8];
  const float* fc_W = (const float*)d_in[9];
  const float* fc_b = (const float*)d_in[10];

  float* ws = (float*)d_ws;
  const size_t NBSD = (size_t)B_ * S_ * D_;   // 2,097,152
  const size_t NBHS = (size_t)B_ * NH_ * S_;  // 32,768
  float* h1 = ws;                      // [B,S,D] f32 (layer-1 output)
  float* ig = h1 + NBSD;
  float* fg = ig + NBHS;
  float* aA = fg + NBHS;
  float* amaxA = aA + NBHS;
  unsigned short* kvhH = (unsigned short*)(amaxA + NBHS);
  unsigned short* kvhL = kvhH + NBSD;
  unsigned short* kvTH = kvhL + NBSD;
  unsigned short* kvTL = kvTH + NBSD;
  unsigned short* hqH = kvTL + NBSD;   // [B,128,512] bf16 hi (layer-2 rows 896..1023)
  unsigned short* hqL = hqH + (size_t)B_ * 128 * D_;
  // total footprint: 26,738,688 bytes == round-6 proven layout

  convkv_kernel<<<B_ * S_, 64, 0, stream>>>(x_enc, kvhH, kvhL);
  transpose_kernel<<<dim3(S_ / 64, NH_, B_), 256, 0, stream>>>(kvhH, kvTH);
  transpose_kernel<<<dim3(S_ / 64, NH_, B_), 256, 0, stream>>>(kvhL, kvTL);

  for (int l = 0; l < L_; ++l) {
    const float* qin = (l == 0) ? x_enc : h1;
    gates2_kernel<<<dim3(S_ / 32, 2, B_), 256, 0, stream>>>(
        qin, x_enc,
        W_ig + (size_t)l * NH_ * 3 * D_, b_ig + (size_t)l * NH_,
        W_fg + (size_t)l * NH_ * 3 * D_, b_fg + (size_t)l * NH_, ig, fg);
    scan_kernel<<<B_ * NH_, 64, 0, stream>>>(ig, fg, aA, amaxA);
    if (l == 0) {
      attn_mfma_kernel<<<dim3(S_ / 64, NH_, B_), 256, 0, stream>>>(
          qin, kvhH, kvhL, kvTH, kvTL, aA, amaxA, ln_w + (size_t)l * D_,
          h1, (unsigned short*)nullptr, (unsigned short*)nullptr, 0, 0, 0, S_);
    } else {
      attn_mfma_kernel<<<dim3(2, NH_, B_), 256, 0, stream>>>(
          qin, kvhH, kvhL, kvTH, kvTL, aA, amaxA, ln_w + (size_t)l * D_,
          (float*)nullptr, hqH, hqL, 1, 14, 896, 128);
    }
  }
  fc3_kernel<<<dim3(6, 8), 256, 0, stream>>>(hqH, hqL, fc_W, fc_b, (float*)d_out);
}